// Round 1
// baseline (604.140 us; speedup 1.0000x reference)
//
#include <hip/hip_runtime.h>
#include <stdint.h>

#define S_LEN 4096
#define HDIM  2048
#define NHEAD 16
#define HD    128
#define WIN   1024

typedef float  f32x4  __attribute__((ext_vector_type(4)));
typedef float  f32x4v __attribute__((ext_vector_type(4)));
typedef __bf16 bf16x8 __attribute__((ext_vector_type(8)));
typedef short  short8 __attribute__((ext_vector_type(8)));
typedef short  short4v __attribute__((ext_vector_type(4)));

static __device__ __forceinline__ short f2bf(float f) {
  union { float f; uint32_t u; } v; v.f = f;
  uint32_t r = (v.u + 0x7FFFu + ((v.u >> 16) & 1u)) >> 16;
  return (short)(uint16_t)r;
}

static __device__ __forceinline__ void gload_lds16(const void* g, void* l) {
  __builtin_amdgcn_global_load_lds((__attribute__((address_space(1))) void*)g,
                                   (__attribute__((address_space(3))) void*)l,
                                   16, 0, 0);
}

// ---------------- RMSNorm: f32 x (4096x2048) -> bf16 xn ----------------
__global__ __launch_bounds__(256) void rmsnorm_k(const float* __restrict__ x,
                                                 const float* __restrict__ w,
                                                 short* __restrict__ xn) {
  const int row = blockIdx.x;
  const int t = threadIdx.x;
  const float* xr = x + (size_t)row * HDIM;
  f32x4v a = *(const f32x4v*)&xr[t * 8];
  f32x4v b = *(const f32x4v*)&xr[t * 8 + 4];
  float ss = a.x*a.x + a.y*a.y + a.z*a.z + a.w*a.w
           + b.x*b.x + b.y*b.y + b.z*b.z + b.w*b.w;
#pragma unroll
  for (int d = 1; d < 64; d <<= 1) ss += __shfl_xor(ss, d, 64);
  __shared__ float sred[4];
  if ((t & 63) == 0) sred[t >> 6] = ss;
  __syncthreads();
  float tot = sred[0] + sred[1] + sred[2] + sred[3];
  float rs = rsqrtf(tot * (1.0f / HDIM) + 1e-5f);
  float vv[8] = {a.x, a.y, a.z, a.w, b.x, b.y, b.z, b.w};
  const float* wp = w + t * 8;
  short8 o;
#pragma unroll
  for (int j = 0; j < 8; ++j) o[j] = f2bf(vv[j] * rs * wp[j]);
  *(short8*)&xn[(size_t)row * HDIM + t * 8] = o;
}

// ---------------- f32 -> bf16 weight convert ----------------
__global__ __launch_bounds__(256) void cvt_k(const float* __restrict__ in,
                                             short* __restrict__ out, int n4) {
  int i = blockIdx.x * 256 + threadIdx.x;
  if (i >= n4) return;
  f32x4v v = *(const f32x4v*)&in[(size_t)i * 4];
  short4v o = { f2bf(v.x), f2bf(v.y), f2bf(v.z), f2bf(v.w) };
  *(short4v*)&out[(size_t)i * 4] = o;
}

// ---------------- 128x128 tile bf16 GEMM, B^T input ----------------
// C[row][col] = sum_k A[row][k] * Bt[col][k]
// EPI==0: store f32 to Cf[row*N+col]
// EPI==1: QKV epilogue: RoPE on first 32 dims of q,k heads; scatter to
//         Q[h][s][d] (pre-scaled 1/sqrt(HD)), K[h][s][d], Vt[h][d][s], bf16.
template <int EPI>
__global__ __launch_bounds__(256) void gemm_bt(
    const short* __restrict__ A, const short* __restrict__ Bt,
    int M, int N, int K, float* __restrict__ Cf,
    const float* __restrict__ cosb, const float* __restrict__ sinb,
    short* __restrict__ Qo, short* __restrict__ Ko, short* __restrict__ Vt) {
  __shared__ __align__(16) short Al[128 * 64];
  __shared__ __align__(16) short Bl[128 * 64];
  const int t = threadIdx.x;
  const int w = t >> 6, l = t & 63;
  const int lr = l & 15, lg = l >> 4;
  const int wr = w >> 1, wc = w & 1;
  const int brow = blockIdx.y * 128, bcol = blockIdx.x * 128;

  f32x4 acc[4][4] = {};

  const int srow = t >> 3;       // 0..31 rows per 4KB issue
  const int scol = (t & 7) * 8;  // bf16 element col (16B per lane)
  const size_t abase = (size_t)(brow + srow) * K + scol;
  const size_t bbase = (size_t)(bcol + srow) * K + scol;

  for (int kt = 0; kt < K; kt += 64) {
#pragma unroll
    for (int i = 0; i < 4; ++i)
      gload_lds16(A + abase + (size_t)(i * 32) * K + kt, &Al[i * 2048 + w * 512]);
#pragma unroll
    for (int i = 0; i < 4; ++i)
      gload_lds16(Bt + bbase + (size_t)(i * 32) * K + kt, &Bl[i * 2048 + w * 512]);
    __syncthreads();
#pragma unroll
    for (int kk = 0; kk < 2; ++kk) {
      bf16x8 af[4], bfm[4];
#pragma unroll
      for (int m = 0; m < 4; ++m)
        af[m] = *(const bf16x8*)&Al[(wr * 64 + m * 16 + lr) * 64 + kk * 32 + lg * 8];
#pragma unroll
      for (int n = 0; n < 4; ++n)
        bfm[n] = *(const bf16x8*)&Bl[(wc * 64 + n * 16 + lr) * 64 + kk * 32 + lg * 8];
#pragma unroll
      for (int m = 0; m < 4; ++m)
#pragma unroll
        for (int n = 0; n < 4; ++n)
          acc[m][n] = __builtin_amdgcn_mfma_f32_16x16x32_bf16(af[m], bfm[n], acc[m][n], 0, 0, 0);
    }
    __syncthreads();
  }

  const int row0 = brow + wr * 64, col0 = bcol + wc * 64;
  if (EPI == 0) {
#pragma unroll
    for (int m = 0; m < 4; ++m)
#pragma unroll
      for (int n = 0; n < 4; ++n)
#pragma unroll
        for (int r = 0; r < 4; ++r)
          Cf[(size_t)(row0 + m * 16 + lg * 4 + r) * N + col0 + n * 16 + lr] = acc[m][n][r];
  } else {
    const int sec = col0 >> 11;                 // 0=q 1=k 2=v
    const int headc = (col0 & 2047) >> 7;       // constant over 64-wide tile
    const bool rope = (sec < 2) && ((col0 & 127) == 0);
#pragma unroll
    for (int m = 0; m < 4; ++m) {
#pragma unroll
      for (int r = 0; r < 4; ++r) {
        const int s = row0 + m * 16 + lg * 4 + r;
        float v0 = acc[m][0][r], v1 = acc[m][1][r];
        float v2 = acc[m][2][r], v3 = acc[m][3][r];
        if (rope) {
          const int d0 = lr;  // 0..15, pairs (d0, d0+16)
          float c0 = cosb[s * 32 + d0],      sn0 = sinb[s * 32 + d0];
          float c1 = cosb[s * 32 + d0 + 16], sn1 = sinb[s * 32 + d0 + 16];
          float t0 = v0 * c0 - v1 * sn0;
          float t1 = v1 * c1 + v0 * sn1;
          v0 = t0; v1 = t1;
        }
        float vv[4] = {v0, v1, v2, v3};
#pragma unroll
        for (int n = 0; n < 4; ++n) {
          const int col = col0 + n * 16 + lr;
          const int d = col & 127;
          if (sec == 0)
            Qo[((size_t)headc * S_LEN + s) * HD + d] = f2bf(vv[n] * 0.08838834764831845f);
          else if (sec == 1)
            Ko[((size_t)headc * S_LEN + s) * HD + d] = f2bf(vv[n]);
          else
            Vt[((size_t)headc * HD + d) * S_LEN + s] = f2bf(vv[n]);
        }
      }
    }
  }
}

// ---------------- sliding-window flash attention ----------------
// grid (S/64, NHEAD), 4 waves/block, wave w owns 16 query rows.
// Q pre-scaled by 1/sqrt(HD). K: [h][s][d]. Vt: [h][d][s]. Out bf16 [s][h*128+d].
__global__ __launch_bounds__(256) void attn_k(const short* __restrict__ Q,
                                              const short* __restrict__ Kk,
                                              const short* __restrict__ Vt,
                                              short* __restrict__ Ao) {
  __shared__ __align__(16) short Pl[4][16 * 40];  // padded stride 40 elems (80B)
  const int head = blockIdx.y;
  const int w = threadIdx.x >> 6, l = threadIdx.x & 63;
  const int lr = l & 15, lg = l >> 4;
  const int q0 = blockIdx.x * 64 + w * 16;
  const short* Qh = Q  + (size_t)head * S_LEN * HD;
  const short* Kh = Kk + (size_t)head * S_LEN * HD;
  const short* Vh = Vt + (size_t)head * HD * S_LEN;

  bf16x8 qf[4];
#pragma unroll
  for (int kk = 0; kk < 4; ++kk)
    qf[kk] = *(const bf16x8*)&Qh[(size_t)(q0 + lr) * HD + kk * 32 + lg * 8];

  f32x4 oacc[8] = {};
  float mrow[4], lrow[4];
#pragma unroll
  for (int r = 0; r < 4; ++r) { mrow[r] = -1e30f; lrow[r] = 0.0f; }

  int kstart = q0 - WIN; if (kstart < 0) kstart = 0; kstart &= ~31;
  const int kend = q0 + 15;

  for (int k0 = kstart; k0 <= kend; k0 += 32) {
    // ---- S = Q K^T (16 q x 32 keys) ----
    bf16x8 kf[2][4];
#pragma unroll
    for (int nf = 0; nf < 2; ++nf)
#pragma unroll
      for (int kk = 0; kk < 4; ++kk)
        kf[nf][kk] = *(const bf16x8*)&Kh[(size_t)(k0 + nf * 16 + lr) * HD + kk * 32 + lg * 8];
    f32x4 sacc[2] = {};
#pragma unroll
    for (int nf = 0; nf < 2; ++nf)
#pragma unroll
      for (int kk = 0; kk < 4; ++kk)
        sacc[nf] = __builtin_amdgcn_mfma_f32_16x16x32_bf16(qf[kk], kf[nf][kk], sacc[nf], 0, 0, 0);

    // prefetch V fragments (independent of softmax)
    bf16x8 vf[8];
#pragma unroll
    for (int df = 0; df < 8; ++df)
      vf[df] = *(const bf16x8*)&Vh[(size_t)(df * 16 + lr) * S_LEN + k0 + lg * 8];

    // ---- online softmax over this 32-key tile ----
    float scl[4];
#pragma unroll
    for (int r = 0; r < 4; ++r) {
      const int i = q0 + lg * 4 + r;
      float sv[2]; bool val[2];
#pragma unroll
      for (int nf = 0; nf < 2; ++nf) {
        const int j = k0 + nf * 16 + lr;
        val[nf] = (j <= i) && (j + WIN >= i);
        sv[nf] = val[nf] ? sacc[nf][r] : -1e30f;
      }
      float mx = fmaxf(sv[0], sv[1]);
#pragma unroll
      for (int d = 1; d < 16; d <<= 1) mx = fmaxf(mx, __shfl_xor(mx, d, 64));
      const float mn = fmaxf(mrow[r], mx);
      const float sc = __expf(mrow[r] - mn);   // mrow finite sentinel: safe
      mrow[r] = mn;
      const float p0 = val[0] ? __expf(sv[0] - mn) : 0.0f;
      const float p1 = val[1] ? __expf(sv[1] - mn) : 0.0f;
      float rs = p0 + p1;
#pragma unroll
      for (int d = 1; d < 16; d <<= 1) rs += __shfl_xor(rs, d, 64);
      lrow[r] = lrow[r] * sc + rs;
      scl[r] = sc;
      Pl[w][(lg * 4 + r) * 40 + lr]      = f2bf(p0);
      Pl[w][(lg * 4 + r) * 40 + 16 + lr] = f2bf(p1);
    }
#pragma unroll
    for (int df = 0; df < 8; ++df)
#pragma unroll
      for (int r = 0; r < 4; ++r) oacc[df][r] *= scl[r];

    // P acc-layout -> A-frag layout via per-wave LDS
    bf16x8 pa = *(const bf16x8*)&Pl[w][lr * 40 + lg * 8];
#pragma unroll
    for (int df = 0; df < 8; ++df)
      oacc[df] = __builtin_amdgcn_mfma_f32_16x16x32_bf16(pa, vf[df], oacc[df], 0, 0, 0);
  }

  float inv[4];
#pragma unroll
  for (int r = 0; r < 4; ++r) inv[r] = 1.0f / lrow[r];
#pragma unroll
  for (int df = 0; df < 8; ++df)
#pragma unroll
    for (int r = 0; r < 4; ++r) {
      const int s = q0 + lg * 4 + r;
      Ao[(size_t)s * HDIM + head * HD + df * 16 + lr] = f2bf(oacc[df][r] * inv[r]);
    }
}

extern "C" void kernel_launch(void* const* d_in, const int* in_sizes, int n_in,
                              void* d_out, int out_size, void* d_ws, size_t ws_size,
                              hipStream_t stream) {
  const float* x    = (const float*)d_in[0];
  const float* cosb = (const float*)d_in[1];
  const float* sinb = (const float*)d_in[2];
  const float* nw   = (const float*)d_in[3];
  const float* qkvw = (const float*)d_in[4];
  const float* ow   = (const float*)d_in[5];
  float* out = (float*)d_out;

  // workspace layout (shorts). xn reused as attention output. wb reused for o_w.
  short* ws = (short*)d_ws;
  short* xn = ws;                               // 4096*2048
  short* wb = xn + (size_t)S_LEN * HDIM;        // 3*2048*2048 (qkv_w bf16, then o_w bf16)
  short* Qb = wb + (size_t)3 * HDIM * HDIM;     // 16*4096*128
  short* Kb = Qb + (size_t)NHEAD * S_LEN * HD;
  short* Vb = Kb + (size_t)NHEAD * S_LEN * HD;
  short* Ao = xn;                               // reuse (xn dead after QKV GEMM)

  rmsnorm_k<<<S_LEN, 256, 0, stream>>>(x, nw, xn);
  cvt_k<<<(3 * HDIM * HDIM / 4 + 255) / 256, 256, 0, stream>>>(qkvw, wb, 3 * HDIM * HDIM / 4);
  gemm_bt<1><<<dim3(3 * HDIM / 128, S_LEN / 128), 256, 0, stream>>>(
      xn, wb, S_LEN, 3 * HDIM, HDIM, nullptr, cosb, sinb, Qb, Kb, Vb);
  cvt_k<<<(HDIM * HDIM / 4 + 255) / 256, 256, 0, stream>>>(ow, wb, HDIM * HDIM / 4);
  attn_k<<<dim3(S_LEN / 64, NHEAD), 256, 0, stream>>>(Qb, Kb, Vb, Ao);
  gemm_bt<0><<<dim3(HDIM / 128, S_LEN / 128), 256, 0, stream>>>(
      Ao, wb, S_LEN, HDIM, HDIM, out, nullptr, nullptr, nullptr, nullptr, nullptr);
}

// Round 2
// 351.015 us; speedup vs baseline: 1.7211x; 1.7211x over previous
//
#include <hip/hip_runtime.h>
#include <stdint.h>

#define S_LEN 4096
#define HDIM  2048
#define NHEAD 16
#define HD    128
#define WIN   1024

typedef float  f32x4  __attribute__((ext_vector_type(4)));
typedef float  f32x4v __attribute__((ext_vector_type(4)));
typedef __bf16 bf16x8 __attribute__((ext_vector_type(8)));
typedef short  short8 __attribute__((ext_vector_type(8)));
typedef short  short4v __attribute__((ext_vector_type(4)));

static __device__ __forceinline__ short f2bf(float f) {
  union { float f; uint32_t u; } v; v.f = f;
  uint32_t r = (v.u + 0x7FFFu + ((v.u >> 16) & 1u)) >> 16;
  return (short)(uint16_t)r;
}

static __device__ __forceinline__ void gload_lds16(const void* g, void* l) {
  __builtin_amdgcn_global_load_lds((__attribute__((address_space(1))) void*)g,
                                   (__attribute__((address_space(3))) void*)l,
                                   16, 0, 0);
}

// ---------------- RMSNorm: f32 x (4096x2048) -> bf16 xn ----------------
__global__ __launch_bounds__(256) void rmsnorm_k(const float* __restrict__ x,
                                                 const float* __restrict__ w,
                                                 short* __restrict__ xn) {
  const int row = blockIdx.x;
  const int t = threadIdx.x;
  const float* xr = x + (size_t)row * HDIM;
  f32x4v a = *(const f32x4v*)&xr[t * 8];
  f32x4v b = *(const f32x4v*)&xr[t * 8 + 4];
  float ss = a.x*a.x + a.y*a.y + a.z*a.z + a.w*a.w
           + b.x*b.x + b.y*b.y + b.z*b.z + b.w*b.w;
#pragma unroll
  for (int d = 1; d < 64; d <<= 1) ss += __shfl_xor(ss, d, 64);
  __shared__ float sred[4];
  if ((t & 63) == 0) sred[t >> 6] = ss;
  __syncthreads();
  float tot = sred[0] + sred[1] + sred[2] + sred[3];
  float rs = rsqrtf(tot * (1.0f / HDIM) + 1e-5f);
  float vv[8] = {a.x, a.y, a.z, a.w, b.x, b.y, b.z, b.w};
  const float* wp = w + t * 8;
  short8 o;
#pragma unroll
  for (int j = 0; j < 8; ++j) o[j] = f2bf(vv[j] * rs * wp[j]);
  *(short8*)&xn[(size_t)row * HDIM + t * 8] = o;
}

// ---------------- f32 -> bf16 weight convert ----------------
__global__ __launch_bounds__(256) void cvt_k(const float* __restrict__ in,
                                             short* __restrict__ out, int n4) {
  int i = blockIdx.x * 256 + threadIdx.x;
  if (i >= n4) return;
  f32x4v v = *(const f32x4v*)&in[(size_t)i * 4];
  short4v o = { f2bf(v.x), f2bf(v.y), f2bf(v.z), f2bf(v.w) };
  *(short4v*)&out[(size_t)i * 4] = o;
}

// ---------------- 128x128 tile bf16 GEMM, B^T input ----------------
template <int EPI>
__global__ __launch_bounds__(256) void gemm_bt(
    const short* __restrict__ A, const short* __restrict__ Bt,
    int M, int N, int K, float* __restrict__ Cf,
    const float* __restrict__ cosb, const float* __restrict__ sinb,
    short* __restrict__ Qo, short* __restrict__ Ko, short* __restrict__ Vt) {
  __shared__ __align__(16) short Al[128 * 64];
  __shared__ __align__(16) short Bl[128 * 64];
  const int t = threadIdx.x;
  const int w = t >> 6, l = t & 63;
  const int lr = l & 15, lg = l >> 4;
  const int wr = w >> 1, wc = w & 1;
  const int brow = blockIdx.y * 128, bcol = blockIdx.x * 128;

  f32x4 acc[4][4] = {};

  const int srow = t >> 3;
  const int scol = (t & 7) * 8;
  const size_t abase = (size_t)(brow + srow) * K + scol;
  const size_t bbase = (size_t)(bcol + srow) * K + scol;

  for (int kt = 0; kt < K; kt += 64) {
#pragma unroll
    for (int i = 0; i < 4; ++i)
      gload_lds16(A + abase + (size_t)(i * 32) * K + kt, &Al[i * 2048 + w * 512]);
#pragma unroll
    for (int i = 0; i < 4; ++i)
      gload_lds16(Bt + bbase + (size_t)(i * 32) * K + kt, &Bl[i * 2048 + w * 512]);
    __syncthreads();
#pragma unroll
    for (int kk = 0; kk < 2; ++kk) {
      bf16x8 af[4], bfm[4];
#pragma unroll
      for (int m = 0; m < 4; ++m)
        af[m] = *(const bf16x8*)&Al[(wr * 64 + m * 16 + lr) * 64 + kk * 32 + lg * 8];
#pragma unroll
      for (int n = 0; n < 4; ++n)
        bfm[n] = *(const bf16x8*)&Bl[(wc * 64 + n * 16 + lr) * 64 + kk * 32 + lg * 8];
#pragma unroll
      for (int m = 0; m < 4; ++m)
#pragma unroll
        for (int n = 0; n < 4; ++n)
          acc[m][n] = __builtin_amdgcn_mfma_f32_16x16x32_bf16(af[m], bfm[n], acc[m][n], 0, 0, 0);
    }
    __syncthreads();
  }

  const int row0 = brow + wr * 64, col0 = bcol + wc * 64;
  if (EPI == 0) {
#pragma unroll
    for (int m = 0; m < 4; ++m)
#pragma unroll
      for (int n = 0; n < 4; ++n)
#pragma unroll
        for (int r = 0; r < 4; ++r)
          Cf[(size_t)(row0 + m * 16 + lg * 4 + r) * N + col0 + n * 16 + lr] = acc[m][n][r];
  } else {
    const int sec = col0 >> 11;
    const int headc = (col0 & 2047) >> 7;
    const bool rope = (sec < 2) && ((col0 & 127) == 0);
#pragma unroll
    for (int m = 0; m < 4; ++m) {
#pragma unroll
      for (int r = 0; r < 4; ++r) {
        const int s = row0 + m * 16 + lg * 4 + r;
        float v0 = acc[m][0][r], v1 = acc[m][1][r];
        float v2 = acc[m][2][r], v3 = acc[m][3][r];
        if (rope) {
          const int d0 = lr;
          float c0 = cosb[s * 32 + d0],      sn0 = sinb[s * 32 + d0];
          float c1 = cosb[s * 32 + d0 + 16], sn1 = sinb[s * 32 + d0 + 16];
          float t0 = v0 * c0 - v1 * sn0;
          float t1 = v1 * c1 + v0 * sn1;
          v0 = t0; v1 = t1;
        }
        float vv[4] = {v0, v1, v2, v3};
#pragma unroll
        for (int n = 0; n < 4; ++n) {
          const int col = col0 + n * 16 + lr;
          const int d = col & 127;
          if (sec == 0)
            Qo[((size_t)headc * S_LEN + s) * HD + d] = f2bf(vv[n] * 0.08838834764831845f);
          else if (sec == 1)
            Ko[((size_t)headc * S_LEN + s) * HD + d] = f2bf(vv[n]);
          else
            Vt[((size_t)headc * HD + d) * S_LEN + s] = f2bf(vv[n]);
        }
      }
    }
  }
}

// ---------------- sliding-window flash attention v2 ----------------
// grid (S/64, NHEAD), 4 waves/block; wave w owns 16 q-rows; block-shared
// KVBLK=64 K/V tiles staged in LDS (global_load_lds, XOR-swizzled layout).
// Q pre-scaled by 1/sqrt(HD). K: [h][s][d]. Vt: [h][d][s]. Out bf16 [s][h*128+d].
__global__ __launch_bounds__(256) void attn_k(const short* __restrict__ Q,
                                              const short* __restrict__ Kk,
                                              const short* __restrict__ Vt,
                                              short* __restrict__ Ao) {
  __shared__ __align__(16) short Kl[64 * HD];    // [64 key][128 d], rows 256B, swizzled
  __shared__ __align__(16) short Vl[HD * 64];    // [128 d][64 key], rows 128B, swizzled
  __shared__ __align__(16) short Pl[4][16 * 72]; // per-wave P, stride 72 shorts
  const int head = blockIdx.y;
  int bxx = blockIdx.x;
  bxx = ((bxx & 7) << 3) | (bxx >> 3);           // XCD-chunked remap (bijective, 64=8x8)
  const int qb = bxx * 64;
  const int w = threadIdx.x >> 6, l = threadIdx.x & 63;
  const int lr = l & 15, lg = l >> 4;
  const int q0w = qb + w * 16;
  const short* Qh = Q  + (size_t)head * S_LEN * HD;
  const short* Kh = Kk + (size_t)head * S_LEN * HD;
  const short* Vh = Vt + (size_t)head * HD * S_LEN;

  bf16x8 qf[4];
#pragma unroll
  for (int kk = 0; kk < 4; ++kk)
    qf[kk] = *(const bf16x8*)&Qh[(size_t)(q0w + lr) * HD + kk * 32 + lg * 8];

  f32x4 oacc[8] = {};
  float mrow[4], lrow[4];
#pragma unroll
  for (int r = 0; r < 4; ++r) { mrow[r] = -1e30f; lrow[r] = 0.0f; }

  const int k_begin = (qb >= WIN) ? (qb - WIN) : 0;
  const int nt = (qb + 64 - k_begin) >> 6;
  const int swz = (lr & 7) << 4;  // byte XOR for K/V tile reads

  for (int tkv = 0; tkv < nt; ++tkv) {
    const int k0 = k_begin + tkv * 64;
    // ---- stage K tile: 64 rows x 256B; inverse-swizzled global source ----
#pragma unroll
    for (int i = 0; i < 4; ++i) {
      const int row = i * 16 + w * 4 + (l >> 4);
      gload_lds16(Kh + (size_t)(k0 + row) * HD + (((l & 15) ^ (row & 7)) * 8),
                  &Kl[(i * 16 + w * 4) * HD]);
    }
    // ---- stage V tile: 128 rows x 128B ----
#pragma unroll
    for (int i = 0; i < 4; ++i) {
      const int row = i * 32 + w * 8 + (l >> 3);
      gload_lds16(Vh + (size_t)row * S_LEN + k0 + (((l & 7) ^ (row & 7)) * 8),
                  &Vl[(i * 32 + w * 8) * 64]);
    }
    __syncthreads();

    // ---- S = Q K^T (16 q x 64 keys) ----
    f32x4 sacc[4] = {};
#pragma unroll
    for (int nf = 0; nf < 4; ++nf) {
      const char* kb = (const char*)Kl + (nf * 16 + lr) * 256;
      bf16x8 kf[4];
#pragma unroll
      for (int kk = 0; kk < 4; ++kk)
        kf[kk] = *(const bf16x8*)(kb + ((kk * 64 + lg * 16) ^ swz));
#pragma unroll
      for (int kk = 0; kk < 4; ++kk)
        sacc[nf] = __builtin_amdgcn_mfma_f32_16x16x32_bf16(qf[kk], kf[nf == nf ? kk : kk], sacc[nf], 0, 0, 0);
    }

    // ---- online softmax ----
    const bool full = (k0 + 63 <= q0w) && (k0 >= q0w + 15 - WIN);
    float scl[4];
#pragma unroll
    for (int r = 0; r < 4; ++r) {
      const int i = q0w + lg * 4 + r;
      float sv[4];
#pragma unroll
      for (int nf = 0; nf < 4; ++nf) sv[nf] = sacc[nf][r];
      if (!full) {
#pragma unroll
        for (int nf = 0; nf < 4; ++nf) {
          const int j = k0 + nf * 16 + lr;
          if (!((j <= i) && (j + WIN >= i))) sv[nf] = -1e30f;
        }
      }
      float mx = fmaxf(fmaxf(sv[0], sv[1]), fmaxf(sv[2], sv[3]));
#pragma unroll
      for (int d = 1; d < 16; d <<= 1) mx = fmaxf(mx, __shfl_xor(mx, d, 64));
      const float mn = fmaxf(mrow[r], mx);
      const float sc = __expf(mrow[r] - mn);
      mrow[r] = mn;
      float p[4], rs = 0.0f;
#pragma unroll
      for (int nf = 0; nf < 4; ++nf) { p[nf] = __expf(sv[nf] - mn); rs += p[nf]; }
#pragma unroll
      for (int d = 1; d < 16; d <<= 1) rs += __shfl_xor(rs, d, 64);
      lrow[r] = lrow[r] * sc + rs;
      scl[r] = sc;
#pragma unroll
      for (int nf = 0; nf < 4; ++nf)
        Pl[w][(lg * 4 + r) * 72 + nf * 16 + lr] = f2bf(p[nf]);
    }
#pragma unroll
    for (int df = 0; df < 8; ++df)
#pragma unroll
      for (int r = 0; r < 4; ++r) oacc[df][r] *= scl[r];

    bf16x8 pa[2];
#pragma unroll
    for (int kk2 = 0; kk2 < 2; ++kk2)
      pa[kk2] = *(const bf16x8*)&Pl[w][lr * 72 + kk2 * 32 + lg * 8];

    // ---- O += P V ----
#pragma unroll
    for (int df = 0; df < 8; ++df) {
      const char* vb = (const char*)Vl + (df * 16 + lr) * 128;
#pragma unroll
      for (int kk2 = 0; kk2 < 2; ++kk2) {
        bf16x8 vfrag = *(const bf16x8*)(vb + ((kk2 * 64 + lg * 16) ^ swz));
        oacc[df] = __builtin_amdgcn_mfma_f32_16x16x32_bf16(pa[kk2], vfrag, oacc[df], 0, 0, 0);
      }
    }
    __syncthreads();
  }

  float inv[4];
#pragma unroll
  for (int r = 0; r < 4; ++r) inv[r] = 1.0f / lrow[r];
#pragma unroll
  for (int df = 0; df < 8; ++df)
#pragma unroll
    for (int r = 0; r < 4; ++r) {
      const int s = q0w + lg * 4 + r;
      Ao[(size_t)s * HDIM + head * HD + df * 16 + lr] = f2bf(oacc[df][r] * inv[r]);
    }
}

extern "C" void kernel_launch(void* const* d_in, const int* in_sizes, int n_in,
                              void* d_out, int out_size, void* d_ws, size_t ws_size,
                              hipStream_t stream) {
  const float* x    = (const float*)d_in[0];
  const float* cosb = (const float*)d_in[1];
  const float* sinb = (const float*)d_in[2];
  const float* nw   = (const float*)d_in[3];
  const float* qkvw = (const float*)d_in[4];
  const float* ow   = (const float*)d_in[5];
  float* out = (float*)d_out;

  short* ws = (short*)d_ws;
  short* xn = ws;
  short* wb = xn + (size_t)S_LEN * HDIM;
  short* Qb = wb + (size_t)3 * HDIM * HDIM;
  short* Kb = Qb + (size_t)NHEAD * S_LEN * HD;
  short* Vb = Kb + (size_t)NHEAD * S_LEN * HD;
  short* Ao = xn;

  rmsnorm_k<<<S_LEN, 256, 0, stream>>>(x, nw, xn);
  cvt_k<<<(3 * HDIM * HDIM / 4 + 255) / 256, 256, 0, stream>>>(qkvw, wb, 3 * HDIM * HDIM / 4);
  gemm_bt<1><<<dim3(3 * HDIM / 128, S_LEN / 128), 256, 0, stream>>>(
      xn, wb, S_LEN, 3 * HDIM, HDIM, nullptr, cosb, sinb, Qb, Kb, Vb);
  cvt_k<<<(HDIM * HDIM / 4 + 255) / 256, 256, 0, stream>>>(ow, wb, HDIM * HDIM / 4);
  attn_k<<<dim3(S_LEN / 64, NHEAD), 256, 0, stream>>>(Qb, Kb, Vb, Ao);
  gemm_bt<0><<<dim3(HDIM / 128, S_LEN / 128), 256, 0, stream>>>(
      Ao, wb, S_LEN, HDIM, HDIM, out, nullptr, nullptr, nullptr, nullptr, nullptr);
}

// Round 3
// 307.099 us; speedup vs baseline: 1.9672x; 1.1430x over previous
//
#include <hip/hip_runtime.h>
#include <stdint.h>

#define S_LEN 4096
#define HDIM  2048
#define NHEAD 16
#define HD    128
#define WIN   1024

typedef float  f32x4  __attribute__((ext_vector_type(4)));
typedef float  f32x4v __attribute__((ext_vector_type(4)));
typedef __bf16 bf16x8 __attribute__((ext_vector_type(8)));
typedef short  short8 __attribute__((ext_vector_type(8)));
typedef short  short4v __attribute__((ext_vector_type(4)));

static __device__ __forceinline__ short f2bf(float f) {
  union { float f; uint32_t u; } v; v.f = f;
  uint32_t r = (v.u + 0x7FFFu + ((v.u >> 16) & 1u)) >> 16;
  return (short)(uint16_t)r;
}

static __device__ __forceinline__ void gload_lds16(const void* g, void* l) {
  __builtin_amdgcn_global_load_lds((__attribute__((address_space(1))) void*)g,
                                   (__attribute__((address_space(3))) void*)l,
                                   16, 0, 0);
}

// ---------------- RMSNorm: f32 x (4096x2048) -> bf16 xn ----------------
__global__ __launch_bounds__(256) void rmsnorm_k(const float* __restrict__ x,
                                                 const float* __restrict__ w,
                                                 short* __restrict__ xn) {
  const int row = blockIdx.x;
  const int t = threadIdx.x;
  const float* xr = x + (size_t)row * HDIM;
  f32x4v a = *(const f32x4v*)&xr[t * 8];
  f32x4v b = *(const f32x4v*)&xr[t * 8 + 4];
  float ss = a.x*a.x + a.y*a.y + a.z*a.z + a.w*a.w
           + b.x*b.x + b.y*b.y + b.z*b.z + b.w*b.w;
#pragma unroll
  for (int d = 1; d < 64; d <<= 1) ss += __shfl_xor(ss, d, 64);
  __shared__ float sred[4];
  if ((t & 63) == 0) sred[t >> 6] = ss;
  __syncthreads();
  float tot = sred[0] + sred[1] + sred[2] + sred[3];
  float rs = rsqrtf(tot * (1.0f / HDIM) + 1e-5f);
  float vv[8] = {a.x, a.y, a.z, a.w, b.x, b.y, b.z, b.w};
  const float* wp = w + t * 8;
  short8 o;
#pragma unroll
  for (int j = 0; j < 8; ++j) o[j] = f2bf(vv[j] * rs * wp[j]);
  *(short8*)&xn[(size_t)row * HDIM + t * 8] = o;
}

// ---------------- f32 -> bf16 weight convert ----------------
__global__ __launch_bounds__(256) void cvt_k(const float* __restrict__ in,
                                             short* __restrict__ out, int n4) {
  int i = blockIdx.x * 256 + threadIdx.x;
  if (i >= n4) return;
  f32x4v v = *(const f32x4v*)&in[(size_t)i * 4];
  short4v o = { f2bf(v.x), f2bf(v.y), f2bf(v.z), f2bf(v.w) };
  *(short4v*)&out[(size_t)i * 4] = o;
}

// ---------------- pipelined 256x128 bf16 GEMM, B^T input ----------------
// 8 waves (4M x 2N), per-wave 64x64 output, BK=64, 3-slot LDS circular buffer.
// Counted vmcnt(6): while computing tile t, tile t+2 stages into slot (t+2)%3.
// T2 XOR swizzle (col8 ^= row&7) on both stage-source and ds_read.
template <int EPI>
__global__ __launch_bounds__(512) void gemm_p(
    const short* __restrict__ A, const short* __restrict__ Bt,
    int M, int N, int K, float* __restrict__ Cf,
    const float* __restrict__ cosb, const float* __restrict__ sinb,
    short* __restrict__ Qo, short* __restrict__ Ko, short* __restrict__ Vt) {
  // per slot: A 256x64 bf16 (16384 shorts) + B 128x64 bf16 (8192 shorts)
  __shared__ __align__(16) short lds[3][24576];
  const int t = threadIdx.x;
  const int wid = t >> 6, l = t & 63;
  const int lr = l & 15, lg = l >> 4;
  const int wm = wid >> 1, wn = wid & 1;

  int bid = blockIdx.x;
  const int nwg = gridDim.x;
  bid = (bid & 7) * (nwg >> 3) + (bid >> 3);   // bijective XCD remap (nwg%8==0)
  const int nbx = N >> 7;
  const int bx = bid % nbx, by = bid / nbx;
  const int brow = by * 256, bcol = bx * 128;

  const int srow7 = (t >> 3) & 7;              // staging row&7
  const int scol = ((t & 7) ^ srow7) * 8;      // inverse-swizzled source col (shorts)

  f32x4 acc[4][4] = {};

  const int nt = K >> 6;

#define STAGE_A(slot, kt, i)                                                     \
  gload_lds16(A + (size_t)(brow + (i) * 64 + (t >> 3)) * K + (kt) + scol,        \
              &lds[slot][(i) * 4096 + t * 8])
#define STAGE_B(slot, kt, i)                                                     \
  gload_lds16(Bt + (size_t)(bcol + (i) * 64 + (t >> 3)) * K + (kt) + scol,       \
              &lds[slot][16384 + (i) * 4096 + t * 8])

  // ---- prologue: stage tiles 0,1 ----
  STAGE_A(0, 0, 0); STAGE_A(0, 0, 1); STAGE_A(0, 0, 2); STAGE_A(0, 0, 3);
  STAGE_B(0, 0, 0); STAGE_B(0, 0, 1);
  STAGE_A(1, 64, 0); STAGE_A(1, 64, 1); STAGE_A(1, 64, 2); STAGE_A(1, 64, 3);
  STAGE_B(1, 64, 0); STAGE_B(1, 64, 1);
  asm volatile("s_waitcnt vmcnt(6)" ::: "memory");   // tile 0 landed
  __builtin_amdgcn_s_barrier();

  const int xo0 = ((lg ^ (lr & 7)) << 3);            // kk=0 read swizzle (shorts)
  const int xo1 = (((4 + lg) ^ (lr & 7)) << 3);      // kk=1

  int slot = 0;
  for (int tt = 0; tt < nt; ++tt) {
    const int s2 = (slot + 2 >= 3) ? slot - 1 : slot + 2;
    const int kt2 = (tt + 2) << 6;
    const bool st = (tt + 2 < nt);
    bf16x8 af[4], bfr[4];

    // ---- phase kk=0 ----
#pragma unroll
    for (int m = 0; m < 4; ++m)
      af[m] = *(const bf16x8*)&lds[slot][(wm * 64 + m * 16 + lr) * 64 + xo0];
#pragma unroll
    for (int n = 0; n < 4; ++n)
      bfr[n] = *(const bf16x8*)&lds[slot][16384 + (wn * 64 + n * 16 + lr) * 64 + xo0];
    if (st) { STAGE_A(s2, kt2, 0); STAGE_A(s2, kt2, 1); STAGE_B(s2, kt2, 0); }
    __builtin_amdgcn_s_barrier();
    asm volatile("s_waitcnt lgkmcnt(0)" ::: "memory");
    __builtin_amdgcn_sched_barrier(0);
    __builtin_amdgcn_s_setprio(1);
#pragma unroll
    for (int m = 0; m < 4; ++m)
#pragma unroll
      for (int n = 0; n < 4; ++n)
        acc[m][n] = __builtin_amdgcn_mfma_f32_16x16x32_bf16(af[m], bfr[n], acc[m][n], 0, 0, 0);
    __builtin_amdgcn_s_setprio(0);
    __builtin_amdgcn_s_barrier();

    // ---- phase kk=1 ----
#pragma unroll
    for (int m = 0; m < 4; ++m)
      af[m] = *(const bf16x8*)&lds[slot][(wm * 64 + m * 16 + lr) * 64 + xo1];
#pragma unroll
    for (int n = 0; n < 4; ++n)
      bfr[n] = *(const bf16x8*)&lds[slot][16384 + (wn * 64 + n * 16 + lr) * 64 + xo1];
    if (st) { STAGE_A(s2, kt2, 2); STAGE_A(s2, kt2, 3); STAGE_B(s2, kt2, 1); }
    if (tt < nt - 2) asm volatile("s_waitcnt vmcnt(6)" ::: "memory");
    else             asm volatile("s_waitcnt vmcnt(0)" ::: "memory");
    __builtin_amdgcn_s_barrier();
    asm volatile("s_waitcnt lgkmcnt(0)" ::: "memory");
    __builtin_amdgcn_sched_barrier(0);
    __builtin_amdgcn_s_setprio(1);
#pragma unroll
    for (int m = 0; m < 4; ++m)
#pragma unroll
      for (int n = 0; n < 4; ++n)
        acc[m][n] = __builtin_amdgcn_mfma_f32_16x16x32_bf16(af[m], bfr[n], acc[m][n], 0, 0, 0);
    __builtin_amdgcn_s_setprio(0);
    __builtin_amdgcn_s_barrier();

    slot = (slot + 1 >= 3) ? 0 : slot + 1;
  }
#undef STAGE_A
#undef STAGE_B

  const int row0 = brow + wm * 64, col0 = bcol + wn * 64;
  if (EPI == 0) {
#pragma unroll
    for (int m = 0; m < 4; ++m)
#pragma unroll
      for (int n = 0; n < 4; ++n)
#pragma unroll
        for (int r = 0; r < 4; ++r)
          Cf[(size_t)(row0 + m * 16 + lg * 4 + r) * N + col0 + n * 16 + lr] = acc[m][n][r];
  } else {
    const int sec = col0 >> 11;
    const int headc = (col0 & 2047) >> 7;
    const bool rope = (sec < 2) && ((col0 & 127) == 0);
#pragma unroll
    for (int m = 0; m < 4; ++m) {
#pragma unroll
      for (int r = 0; r < 4; ++r) {
        const int s = row0 + m * 16 + lg * 4 + r;
        float v0 = acc[m][0][r], v1 = acc[m][1][r];
        float v2 = acc[m][2][r], v3 = acc[m][3][r];
        if (rope) {
          const int d0 = lr;
          float c0 = cosb[s * 32 + d0],      sn0 = sinb[s * 32 + d0];
          float c1 = cosb[s * 32 + d0 + 16], sn1 = sinb[s * 32 + d0 + 16];
          float t0 = v0 * c0 - v1 * sn0;
          float t1 = v1 * c1 + v0 * sn1;
          v0 = t0; v1 = t1;
        }
        float vv[4] = {v0, v1, v2, v3};
#pragma unroll
        for (int n = 0; n < 4; ++n) {
          const int col = col0 + n * 16 + lr;
          const int d = col & 127;
          if (sec == 0)
            Qo[((size_t)headc * S_LEN + s) * HD + d] = f2bf(vv[n] * 0.08838834764831845f);
          else if (sec == 1)
            Ko[((size_t)headc * S_LEN + s) * HD + d] = f2bf(vv[n]);
          else
            Vt[((size_t)headc * HD + d) * S_LEN + s] = f2bf(vv[n]);
        }
      }
    }
  }
}

// ---------------- sliding-window flash attention ----------------
__global__ __launch_bounds__(256) void attn_k(const short* __restrict__ Q,
                                              const short* __restrict__ Kk,
                                              const short* __restrict__ Vt,
                                              short* __restrict__ Ao) {
  __shared__ __align__(16) short Kl[64 * HD];
  __shared__ __align__(16) short Vl[HD * 64];
  __shared__ __align__(16) short Pl[4][16 * 72];
  const int head = blockIdx.y;
  int bxx = blockIdx.x;
  bxx = ((bxx & 7) << 3) | (bxx >> 3);
  const int qb = bxx * 64;
  const int w = threadIdx.x >> 6, l = threadIdx.x & 63;
  const int lr = l & 15, lg = l >> 4;
  const int q0w = qb + w * 16;
  const short* Qh = Q  + (size_t)head * S_LEN * HD;
  const short* Kh = Kk + (size_t)head * S_LEN * HD;
  const short* Vh = Vt + (size_t)head * HD * S_LEN;

  bf16x8 qf[4];
#pragma unroll
  for (int kk = 0; kk < 4; ++kk)
    qf[kk] = *(const bf16x8*)&Qh[(size_t)(q0w + lr) * HD + kk * 32 + lg * 8];

  f32x4 oacc[8] = {};
  float mrow[4], lrow[4];
#pragma unroll
  for (int r = 0; r < 4; ++r) { mrow[r] = -1e30f; lrow[r] = 0.0f; }

  const int k_begin = (qb >= WIN) ? (qb - WIN) : 0;
  const int nt = (qb + 64 - k_begin) >> 6;
  const int swz = (lr & 7) << 4;

  for (int tkv = 0; tkv < nt; ++tkv) {
    const int k0 = k_begin + tkv * 64;
#pragma unroll
    for (int i = 0; i < 4; ++i) {
      const int row = i * 16 + w * 4 + (l >> 4);
      gload_lds16(Kh + (size_t)(k0 + row) * HD + (((l & 15) ^ (row & 7)) * 8),
                  &Kl[(i * 16 + w * 4) * HD]);
    }
#pragma unroll
    for (int i = 0; i < 4; ++i) {
      const int row = i * 32 + w * 8 + (l >> 3);
      gload_lds16(Vh + (size_t)row * S_LEN + k0 + (((l & 7) ^ (row & 7)) * 8),
                  &Vl[(i * 32 + w * 8) * 64]);
    }
    __syncthreads();

    f32x4 sacc[4] = {};
#pragma unroll
    for (int nf = 0; nf < 4; ++nf) {
      const char* kb = (const char*)Kl + (nf * 16 + lr) * 256;
      bf16x8 kf[4];
#pragma unroll
      for (int kk = 0; kk < 4; ++kk)
        kf[kk] = *(const bf16x8*)(kb + ((kk * 64 + lg * 16) ^ swz));
#pragma unroll
      for (int kk = 0; kk < 4; ++kk)
        sacc[nf] = __builtin_amdgcn_mfma_f32_16x16x32_bf16(qf[kk], kf[kk], sacc[nf], 0, 0, 0);
    }

    const bool full = (k0 + 63 <= q0w) && (k0 >= q0w + 15 - WIN);
    float scl[4];
#pragma unroll
    for (int r = 0; r < 4; ++r) {
      const int i = q0w + lg * 4 + r;
      float sv[4];
#pragma unroll
      for (int nf = 0; nf < 4; ++nf) sv[nf] = sacc[nf][r];
      if (!full) {
#pragma unroll
        for (int nf = 0; nf < 4; ++nf) {
          const int j = k0 + nf * 16 + lr;
          if (!((j <= i) && (j + WIN >= i))) sv[nf] = -1e30f;
        }
      }
      float mx = fmaxf(fmaxf(sv[0], sv[1]), fmaxf(sv[2], sv[3]));
#pragma unroll
      for (int d = 1; d < 16; d <<= 1) mx = fmaxf(mx, __shfl_xor(mx, d, 64));
      const float mn = fmaxf(mrow[r], mx);
      const float sc = __expf(mrow[r] - mn);
      mrow[r] = mn;
      float p[4], rs = 0.0f;
#pragma unroll
      for (int nf = 0; nf < 4; ++nf) { p[nf] = __expf(sv[nf] - mn); rs += p[nf]; }
#pragma unroll
      for (int d = 1; d < 16; d <<= 1) rs += __shfl_xor(rs, d, 64);
      lrow[r] = lrow[r] * sc + rs;
      scl[r] = sc;
#pragma unroll
      for (int nf = 0; nf < 4; ++nf)
        Pl[w][(lg * 4 + r) * 72 + nf * 16 + lr] = f2bf(p[nf]);
    }
#pragma unroll
    for (int df = 0; df < 8; ++df)
#pragma unroll
      for (int r = 0; r < 4; ++r) oacc[df][r] *= scl[r];

    bf16x8 pa[2];
#pragma unroll
    for (int kk2 = 0; kk2 < 2; ++kk2)
      pa[kk2] = *(const bf16x8*)&Pl[w][lr * 72 + kk2 * 32 + lg * 8];

#pragma unroll
    for (int df = 0; df < 8; ++df) {
      const char* vb = (const char*)Vl + (df * 16 + lr) * 128;
#pragma unroll
      for (int kk2 = 0; kk2 < 2; ++kk2) {
        bf16x8 vfrag = *(const bf16x8*)(vb + ((kk2 * 64 + lg * 16) ^ swz));
        oacc[df] = __builtin_amdgcn_mfma_f32_16x16x32_bf16(pa[kk2], vfrag, oacc[df], 0, 0, 0);
      }
    }
    __syncthreads();
  }

  float inv[4];
#pragma unroll
  for (int r = 0; r < 4; ++r) inv[r] = 1.0f / lrow[r];
#pragma unroll
  for (int df = 0; df < 8; ++df)
#pragma unroll
    for (int r = 0; r < 4; ++r) {
      const int s = q0w + lg * 4 + r;
      Ao[(size_t)s * HDIM + head * HD + df * 16 + lr] = f2bf(oacc[df][r] * inv[r]);
    }
}

extern "C" void kernel_launch(void* const* d_in, const int* in_sizes, int n_in,
                              void* d_out, int out_size, void* d_ws, size_t ws_size,
                              hipStream_t stream) {
  const float* x    = (const float*)d_in[0];
  const float* cosb = (const float*)d_in[1];
  const float* sinb = (const float*)d_in[2];
  const float* nw   = (const float*)d_in[3];
  const float* qkvw = (const float*)d_in[4];
  const float* ow   = (const float*)d_in[5];
  float* out = (float*)d_out;

  short* ws = (short*)d_ws;
  short* xn = ws;
  short* wb = xn + (size_t)S_LEN * HDIM;
  short* Qb = wb + (size_t)3 * HDIM * HDIM;
  short* Kb = Qb + (size_t)NHEAD * S_LEN * HD;
  short* Vb = Kb + (size_t)NHEAD * S_LEN * HD;
  short* Ao = xn;

  rmsnorm_k<<<S_LEN, 256, 0, stream>>>(x, nw, xn);
  cvt_k<<<(3 * HDIM * HDIM / 4 + 255) / 256, 256, 0, stream>>>(qkvw, wb, 3 * HDIM * HDIM / 4);
  gemm_p<1><<<(3 * HDIM / 128) * (S_LEN / 256), 512, 0, stream>>>(
      xn, wb, S_LEN, 3 * HDIM, HDIM, nullptr, cosb, sinb, Qb, Kb, Vb);
  cvt_k<<<(HDIM * HDIM / 4 + 255) / 256, 256, 0, stream>>>(ow, wb, HDIM * HDIM / 4);
  attn_k<<<dim3(S_LEN / 64, NHEAD), 256, 0, stream>>>(Qb, Kb, Vb, Ao);
  gemm_p<0><<<(HDIM / 128) * (S_LEN / 256), 512, 0, stream>>>(
      Ao, wb, S_LEN, HDIM, HDIM, out, nullptr, nullptr, nullptr, nullptr, nullptr);
}